// Round 7
// baseline (230.800 us; speedup 1.0000x reference)
//
#include <hip/hip_runtime.h>

// BiCutLoss: output [B,L,2] f32, labels [B,L] i32 -> scalar f32.
// Per row: cut = last j with out1 <= out0 (else L); loss = sum_{j<cut} out1*r1 / B.
// r1 = (label==1) ? -3.6/log2(j+2) : 0.065.
//
// Round-4 lesson: VGPR_Count=24 => compiler recycled load-dest registers and
// serialized the load burst (MLP~2). This version forces a fat VGPR budget
// (__launch_bounds__(256,2)) and stages the full row per block:
// 8 float4 (output) + 8 int2 (labels) = 16 loads in flight per thread.

#define LROW 4096
#define BROW 4096
#define BDIM 256
#define KITER (LROW / 2 / BDIM)   // 8 float4-pairs (16 elements) per thread

__global__ __launch_bounds__(BDIM, 2) void bicut_partial_kernel(
    const float* __restrict__ out,
    const int* __restrict__ labels,
    float* __restrict__ partial) {
    const int row = blockIdx.x;
    const int tid = threadIdx.x;
    const float4* rowp4 = reinterpret_cast<const float4*>(out + (size_t)row * 2 * LROW);
    const int2* labp2 = reinterpret_cast<const int2*>(labels + (size_t)row * LROW);

    // Issue ALL output loads first (zmax needs them), then labels (latency
    // hides under the zmax reduce + barrier).
    float4 o[KITER];
    int2 lb[KITER];
#pragma unroll
    for (int k = 0; k < KITER; ++k) o[k] = rowp4[k * BDIM + tid];
#pragma unroll
    for (int k = 0; k < KITER; ++k) lb[k] = labp2[k * BDIM + tid];

    int zmax = -1;  // last j with temp==0, i.e. !(out1 > out0)  (argmax tie -> 0)
#pragma unroll
    for (int k = 0; k < KITER; ++k) {
        const int p = k * BDIM + tid;
        if (!(o[k].y > o[k].x)) zmax = 2 * p;
        if (!(o[k].w > o[k].z)) zmax = 2 * p + 1;
    }

    // ---- block-reduce max(zmax) over 4 waves ----
    __shared__ int smax[BDIM / 64];
    __shared__ float ssum[BDIM / 64];
    const int wid = tid >> 6, lane = tid & 63;
#pragma unroll
    for (int off = 32; off; off >>= 1) zmax = max(zmax, __shfl_down(zmax, off));
    if (lane == 0) smax[wid] = zmax;
    __syncthreads();
    const int mall = max(max(smax[0], smax[1]), max(smax[2], smax[3]));
    const int cut = (mall < 0) ? LROW : mall;  // all-ones row => cut = L

    // ---- masked sum from staged registers ----
    float s = 0.0f;
#pragma unroll
    for (int k = 0; k < KITER; ++k) {
        const int p = k * BDIM + tid;
        const int j0 = 2 * p, j1 = j0 + 1;
        // -3.6/log2(j+2) via v_log_f32 + v_rcp_f32 (rel err ~1e-6 vs 2.8e-3 thr)
        const float pr0 = -3.6f * __builtin_amdgcn_rcpf(__log2f((float)j0 + 2.0f));
        const float pr1 = -3.6f * __builtin_amdgcn_rcpf(__log2f((float)j1 + 2.0f));
        const float t0 = o[k].y * ((lb[k].x == 1) ? pr0 : 0.065f);
        const float t1 = o[k].w * ((lb[k].y == 1) ? pr1 : 0.065f);
        if (j0 < cut) s += t0;
        if (j1 < cut) s += t1;
    }
#pragma unroll
    for (int off = 32; off; off >>= 1) s += __shfl_down(s, off);
    if (lane == 0) ssum[wid] = s;
    __syncthreads();
    if (tid == 0)
        partial[row] = ssum[0] + ssum[1] + ssum[2] + ssum[3];
}

__global__ __launch_bounds__(256) void bicut_final_kernel(
    const float* __restrict__ partial,
    float* __restrict__ loss) {
    const int tid = threadIdx.x;
    const float4* p4 = reinterpret_cast<const float4*>(partial);
    float s = 0.0f;
#pragma unroll
    for (int k = 0; k < BROW / 4 / 256; ++k) {  // 4096 floats = 1024 float4s
        const float4 v = p4[k * 256 + tid];
        s += v.x + v.y + v.z + v.w;
    }
    __shared__ float ss[4];
    const int wid = tid >> 6, lane = tid & 63;
#pragma unroll
    for (int off = 32; off; off >>= 1) s += __shfl_down(s, off);
    if (lane == 0) ss[wid] = s;
    __syncthreads();
    if (tid == 0) loss[0] = (ss[0] + ss[1] + ss[2] + ss[3]) * (1.0f / (float)BROW);
}

extern "C" void kernel_launch(void* const* d_in, const int* in_sizes, int n_in,
                              void* d_out, int out_size, void* d_ws, size_t ws_size,
                              hipStream_t stream) {
    const float* out = (const float*)d_in[0];
    const int* labels = (const int*)d_in[1];
    float* loss = (float*)d_out;
    float* partial = (float*)d_ws;  // 4096 floats = 16 KB, written before read

    bicut_partial_kernel<<<BROW, BDIM, 0, stream>>>(out, labels, partial);
    bicut_final_kernel<<<1, 256, 0, stream>>>(partial, loss);
}

// Round 8
// 230.634 us; speedup vs baseline: 1.0007x; 1.0007x over previous
//
#include <hip/hip_runtime.h>

// BiCutLoss: output [B,L,2] f32, labels [B,L] i32 -> scalar f32.
// Per row: cut = last j with out1 <= out0 (else L); loss = sum_{j<cut} out1*r1 / B.
// r1 = (label==1) ? -3.6/log2(j+2) : 0.065.
//
// Round-7 lesson: register-staged loads get sunk by the compiler (VGPR=36,
// MLP~3) no matter what launch_bounds says -> 78us, 16% HBM. This version
// stages via __builtin_amdgcn_global_load_lds (no VGPR destination => nothing
// to recycle => all 12 copies/wave issued back-to-back into the vmcnt queue).
// 48KB LDS/block, 3 blocks/CU, 36MB outstanding chip-wide => BW-bound.

#define LROW 4096
#define BROW 4096
#define BDIM 256

#define GLOAD_LDS16(g, l)                                                     \
    __builtin_amdgcn_global_load_lds(                                         \
        (const __attribute__((address_space(1))) void*)(g),                   \
        (__attribute__((address_space(3))) void*)(l), 16, 0, 0)

__global__ __launch_bounds__(BDIM) void bicut_partial_kernel(
    const float* __restrict__ out,
    const int* __restrict__ labels,
    float* __restrict__ partial) {
    // 32KB row of output + 16KB labels, staged linearly (no swizzle: contiguous
    // per-lane order matches global_load_lds' wave-uniform-base + lane*16 rule).
    __shared__ alignas(16) float s_out[2 * LROW];  // 32768 B
    __shared__ alignas(16) int s_lab[LROW];        // 16384 B

    const int row = blockIdx.x;
    const int tid = threadIdx.x;
    const char* gout = (const char*)(out + (size_t)row * 2 * LROW);
    const char* glab = (const char*)(labels + (size_t)row * LROW);
    char* lout = (char*)s_out;
    char* llab = (char*)s_lab;

    // Issue ALL stage copies (12 instructions/wave, no dest regs, vmcnt queue).
#pragma unroll
    for (int k = 0; k < 8; ++k) {  // 8 * 256 * 16B = 32KB output row
        const int off = (k * BDIM + tid) * 16;
        GLOAD_LDS16(gout + off, lout + off);
    }
#pragma unroll
    for (int k = 0; k < 4; ++k) {  // 4 * 256 * 16B = 16KB labels
        const int off = (k * BDIM + tid) * 16;
        GLOAD_LDS16(glab + off, llab + off);
    }
    __syncthreads();  // compiler emits s_waitcnt vmcnt(0) before s_barrier

    const float4* so4 = reinterpret_cast<const float4*>(s_out);
    const int2* sl2 = reinterpret_cast<const int2*>(s_lab);

    // ---- pass 1 over LDS: last j with temp==0 (argmax tie -> 0) ----
    int zmax = -1;
#pragma unroll
    for (int k = 0; k < 8; ++k) {
        const int p = k * BDIM + tid;
        const float4 o = so4[p];  // (ch0[2p], ch1[2p], ch0[2p+1], ch1[2p+1])
        if (!(o.y > o.x)) zmax = 2 * p;
        if (!(o.w > o.z)) zmax = 2 * p + 1;
    }

    __shared__ int smax[BDIM / 64];
    __shared__ float ssum[BDIM / 64];
    const int wid = tid >> 6, lane = tid & 63;
#pragma unroll
    for (int off = 32; off; off >>= 1) zmax = max(zmax, __shfl_down(zmax, off));
    if (lane == 0) smax[wid] = zmax;
    __syncthreads();
    const int mall = max(max(smax[0], smax[1]), max(smax[2], smax[3]));
    const int cut = (mall < 0) ? LROW : mall;  // all-ones row => cut = L

    // ---- pass 2 over LDS: masked reward sum ----
    float s = 0.0f;
#pragma unroll
    for (int k = 0; k < 8; ++k) {
        const int p = k * BDIM + tid;
        const float4 o = so4[p];
        const int2 lb = sl2[p];
        const int j0 = 2 * p, j1 = j0 + 1;
        // -3.6/log2(j+2) via v_log_f32 + v_rcp_f32 (rel err ~1e-6 vs 2.8e-3 thr)
        const float pr0 = -3.6f * __builtin_amdgcn_rcpf(__log2f((float)j0 + 2.0f));
        const float pr1 = -3.6f * __builtin_amdgcn_rcpf(__log2f((float)j1 + 2.0f));
        const float t0 = o.y * ((lb.x == 1) ? pr0 : 0.065f);
        const float t1 = o.w * ((lb.y == 1) ? pr1 : 0.065f);
        if (j0 < cut) s += t0;
        if (j1 < cut) s += t1;
    }
#pragma unroll
    for (int off = 32; off; off >>= 1) s += __shfl_down(s, off);
    if (lane == 0) ssum[wid] = s;
    __syncthreads();
    if (tid == 0)
        partial[row] = ssum[0] + ssum[1] + ssum[2] + ssum[3];
}

__global__ __launch_bounds__(256) void bicut_final_kernel(
    const float* __restrict__ partial,
    float* __restrict__ loss) {
    const int tid = threadIdx.x;
    const float4* p4 = reinterpret_cast<const float4*>(partial);
    float s = 0.0f;
#pragma unroll
    for (int k = 0; k < BROW / 4 / 256; ++k) {  // 4096 floats = 1024 float4s
        const float4 v = p4[k * 256 + tid];
        s += v.x + v.y + v.z + v.w;
    }
    __shared__ float ss[4];
    const int wid = tid >> 6, lane = tid & 63;
#pragma unroll
    for (int off = 32; off; off >>= 1) s += __shfl_down(s, off);
    if (lane == 0) ss[wid] = s;
    __syncthreads();
    if (tid == 0) loss[0] = (ss[0] + ss[1] + ss[2] + ss[3]) * (1.0f / (float)BROW);
}

extern "C" void kernel_launch(void* const* d_in, const int* in_sizes, int n_in,
                              void* d_out, int out_size, void* d_ws, size_t ws_size,
                              hipStream_t stream) {
    const float* out = (const float*)d_in[0];
    const int* labels = (const int*)d_in[1];
    float* loss = (float*)d_out;
    float* partial = (float*)d_ws;  // 4096 floats = 16 KB, written before read

    bicut_partial_kernel<<<BROW, BDIM, 0, stream>>>(out, labels, partial);
    bicut_final_kernel<<<1, 256, 0, stream>>>(partial, loss);
}